// Round 7
// baseline (248.843 us; speedup 1.0000x reference)
//
#include <hip/hip_runtime.h>
#include <hip/hip_bf16.h>

// DeepseekMoE fused, top-2 SPARSE routed experts.
// r7: all GEMMs use the m97-proven 128x128 block / 64x64-per-wave shape to get
// past the LDS-read-BW wall (r6 was 64x64 tiles: 48KB LDS reads per 77cyc of
// MFMA -> 18% MfmaUtil ceiling). gemm1 runs dual G/U accumulators per wave
// (ratio 2.67x); gemm2 is the plain m97 shape (ratio 4).
// T=4096, H=1024, E=8, I=512, IS=1024. Buckets 128-aligned (rows<=9208).

typedef short  s16x8 __attribute__((ext_vector_type(8)));
typedef __bf16 bf16x8 __attribute__((ext_vector_type(8)));
typedef float  f32x4 __attribute__((ext_vector_type(4)));

__device__ __forceinline__ float b2f(ushort u) {
  union { unsigned int i; float f; } v; v.i = ((unsigned int)u) << 16; return v.f;
}
__device__ __forceinline__ ushort f2b(float f) {
  union { float f; unsigned int i; } v; v.f = f;
  unsigned int r = v.i + 0x7fffu + ((v.i >> 16) & 1u);
  return (ushort)(r >> 16);
}
__device__ __forceinline__ f32x4 mfma_bf16(s16x8 a, s16x8 b, f32x4 c) {
  return __builtin_amdgcn_mfma_f32_16x16x32_bf16(
      __builtin_bit_cast(bf16x8, a), __builtin_bit_cast(bf16x8, b), c, 0, 0, 0);
}
__device__ __forceinline__ void gll16(const ushort* g, const ushort* l) {
  __builtin_amdgcn_global_load_lds(
      (const __attribute__((address_space(1))) unsigned int*)g,
      (__attribute__((address_space(3))) unsigned int*)l, 16, 0, 0);
}

// -------- tiled transpose + cast, 3 tight-grid variants ----------------------
template<int MODE>
__global__ __launch_bounds__(256) void transpose_k(
    const float* __restrict__ S0, const float* __restrict__ S1,
    const float* __restrict__ S2, ushort* __restrict__ D0,
    ushort* __restrict__ D1, ushort* __restrict__ D2)
{
  const int z = blockIdx.z;
  const float* src; ushort* dst; int srcLd, dstLd;
  if (MODE == 0) {
    src = (z < 8 ? S0 + (size_t)z * 512 * 1024 : S1 + (size_t)(z - 8) * 512 * 1024);
    dst = (z < 8 ? D0 + (size_t)z * 512 * 1024 : D1 + (size_t)(z - 8) * 512 * 1024);
    srcLd = 512; dstLd = 1024;
  } else if (MODE == 1) {
    src = S0 + (size_t)z * 512 * 1024; dst = D0 + (size_t)z * 512;
    srcLd = 1024; dstLd = 5120;
  } else {
    src = (z == 0 ? S0 : z == 1 ? S1 : S2);
    dst = (z == 0 ? D0 : z == 1 ? D1 : D2);
    srcLd = 1024; dstLd = (z == 2 ? 5120 : 1024);
  }
  __shared__ float tile[32][33];
  const int c0 = blockIdx.x * 32, r0 = blockIdx.y * 32;
  const int tx = threadIdx.x & 31, ty = threadIdx.x >> 5;
#pragma unroll
  for (int j = 0; j < 4; ++j)
    tile[ty + j * 8][tx] = src[(size_t)(r0 + ty + j * 8) * srcLd + c0 + tx];
  __syncthreads();
#pragma unroll
  for (int j = 0; j < 4; ++j)
    dst[(size_t)(c0 + ty + j * 8) * dstLd + r0 + tx] = f2b(tile[tx][ty + j * 8]);
}

// ---------------- router (f32) + X->bf16 cast --------------------------------
__global__ __launch_bounds__(256) void router_k(
    const float* __restrict__ X, const float* __restrict__ Gw,
    const float* __restrict__ Temb, const int* __restrict__ task_id,
    const float* __restrict__ Wc, float* __restrict__ scales,
    int* __restrict__ topk, ushort* __restrict__ Xb)
{
  const int wid = threadIdx.x >> 6, lane = threadIdx.x & 63;
  const int t = blockIdx.x * 4 + wid;
  const float* xr = X + t * 1024;
  const float* er = Temb + task_id[0] * 1024;

  float x[16], xe[16];
#pragma unroll
  for (int c = 0; c < 4; ++c) {
    float4 v = *(const float4*)&xr[c * 256 + lane * 4];
    float4 e = *(const float4*)&er[c * 256 + lane * 4];
    x[c * 4 + 0] = v.x; x[c * 4 + 1] = v.y; x[c * 4 + 2] = v.z; x[c * 4 + 3] = v.w;
    xe[c * 4 + 0] = v.x + e.x; xe[c * 4 + 1] = v.y + e.y;
    xe[c * 4 + 2] = v.z + e.z; xe[c * 4 + 3] = v.w + e.w;
  }
#pragma unroll
  for (int c = 0; c < 4; ++c) {
    ushort4 o;
    o.x = f2b(x[c * 4 + 0]); o.y = f2b(x[c * 4 + 1]);
    o.z = f2b(x[c * 4 + 2]); o.w = f2b(x[c * 4 + 3]);
    *(ushort4*)&Xb[t * 1024 + c * 256 + lane * 4] = o;
  }
  float logit[8];
#pragma unroll
  for (int e = 0; e < 8; ++e) {
    float p = 0.f;
#pragma unroll
    for (int c = 0; c < 4; ++c) {
      float4 g = *(const float4*)&Gw[e * 1024 + c * 256 + lane * 4];
      p += xe[c * 4] * g.x + xe[c * 4 + 1] * g.y + xe[c * 4 + 2] * g.z + xe[c * 4 + 3] * g.w;
    }
#pragma unroll
    for (int off = 32; off; off >>= 1) p += __shfl_xor(p, off);
    logit[e] = p;
  }
  float m = logit[0];
#pragma unroll
  for (int e = 1; e < 8; ++e) m = fmaxf(m, logit[e]);
  float pr[8], s = 0.f;
#pragma unroll
  for (int e = 0; e < 8; ++e) { pr[e] = expf(logit[e] - m); s += pr[e]; }
  float inv = 1.f / s;
#pragma unroll
  for (int e = 0; e < 8; ++e) pr[e] *= inv;
  int i1 = 0; float m1 = pr[0];
#pragma unroll
  for (int e = 1; e < 8; ++e) if (pr[e] > m1) { m1 = pr[e]; i1 = e; }
  int i2 = -1; float m2 = -1.f;
#pragma unroll
  for (int e = 0; e < 8; ++e) if (e != i1 && pr[e] > m2) { m2 = pr[e]; i2 = e; }
  float dn = 1.f / (m1 + m2 + 1e-20f);
  float w1 = m1 * dn, w2 = m2 * dn;

  float a0 = 0.f, a1 = 0.f;
#pragma unroll
  for (int c = 0; c < 4; ++c)
#pragma unroll
    for (int j = 0; j < 4; ++j) {
      int h = c * 256 + lane * 4 + j;
      a0 += x[c * 4 + j] * Wc[h * 2];
      a1 += x[c * 4 + j] * Wc[h * 2 + 1];
    }
#pragma unroll
  for (int off = 32; off; off >>= 1) {
    a0 += __shfl_xor(a0, off); a1 += __shfl_xor(a1, off);
  }
  float am = fmaxf(a0, a1);
  float ea0 = expf(a0 - am), ea1 = expf(a1 - am);
  float al0 = ea0 / (ea0 + ea1), al1 = ea1 / (ea0 + ea1);

  if (lane == 0) {
    scales[t * 4 + 0] = al0 * w1;
    scales[t * 4 + 1] = al0 * w2;
    scales[t * 4 + 2] = al1;
    topk[t * 2 + 0] = i1;
    topk[t * 2 + 1] = i2;
  }
}

// ---------------- index build: per-expert 128-aligned token buckets ----------
// meta[0..71] = row-block -> expert; meta[127] = total 128-row blocks.
__global__ __launch_bounds__(256) void indexbuild_k(
    const int* __restrict__ topk, const float* __restrict__ scales,
    int* __restrict__ tokmap, int* __restrict__ tokrows,
    float* __restrict__ rowscale, int* __restrict__ meta)
{
  __shared__ int cnt[8], cnt2[8], base[8];
  const int tid = threadIdx.x;
  if (tid < 8) { cnt[tid] = 0; cnt2[tid] = 0; }
  __syncthreads();
  for (int t = tid; t < 4096; t += 256) {
    atomicAdd(&cnt[topk[t * 2]], 1);
    atomicAdd(&cnt[topk[t * 2 + 1]], 1);
  }
  __syncthreads();
  if (tid == 0) {
    int nb = 0;
    for (int e = 0; e < 8; ++e) {
      base[e] = nb * 128;
      int blocks = (cnt[e] + 127) >> 7;
      for (int j = 0; j < blocks; ++j) meta[nb + j] = e;
      nb += blocks;
    }
    meta[127] = nb;
  }
  __syncthreads();
  for (int t = tid; t < 4096; t += 256) {
#pragma unroll
    for (int r = 0; r < 2; ++r) {
      int e = topk[t * 2 + r];
      int slot = atomicAdd(&cnt2[e], 1);
      int row = base[e] + slot;
      tokmap[row] = t;
      rowscale[row] = scales[t * 4 + r];
      tokrows[t * 2 + r] = row;
    }
  }
  __syncthreads();
  for (int e = 0; e < 8; ++e) {
    int c = cnt[e], R = ((c + 127) >> 7) << 7;
    for (int j = c + tid; j < R; j += 256) {
      tokmap[base[e] + j] = 0;
      rowscale[base[e] + j] = 0.f;
    }
  }
}

// ------- MERGED GEMM1: routed + shared gate/up, 128x128 tiles ----------------
// grid (8, 104). y<72: routed 128-row expert block (x<4, y<meta[127]),
//                y>=72: shared token block (all 8 x).
// 4 waves (2x2), wave = 64x64 output with DUAL G/U accumulators.
// Per kc: 12 ds_read_b128, 32 MFMA (ratio 2.67). LDS 48KB single-buffered.
__global__ __launch_bounds__(256) void gemm1_k(
    const ushort* __restrict__ Xb, const ushort* __restrict__ GT,
    const ushort* __restrict__ UT, const float* __restrict__ scales,
    const int* __restrict__ tokmap, const float* __restrict__ rowscale,
    const int* __restrict__ meta, ushort* __restrict__ Bg,
    ushort* __restrict__ Bs)
{
  __shared__ __align__(16) ushort lA[128 * 64];
  __shared__ __align__(16) ushort lG[128 * 64];
  __shared__ __align__(16) ushort lU[128 * 64];
  const int x = blockIdx.x, y = blockIdx.y;
  const bool routed = y < 72;
  if (routed && (x >= 4 || y >= meta[127])) return;

  const int tid = threadIdx.x, wid = tid >> 6, lane = tid & 63;
  const int col0 = x * 128;
  const int row0 = routed ? y * 128 : (y - 72) * 128;
  const int colG = routed ? (meta[y] * 512 + col0) : (4096 + col0);
  const int wr = (wid >> 1) * 64, wc = (wid & 1) * 64;
  ushort* __restrict__ Out = routed ? Bg : Bs;
  const int outLd = routed ? 512 : 1024;

  // staging: physical 16B chunk (r,c) holds logical chunk c^(r&7) (XOR swizzle
  // on the GLOBAL source address; LDS destination stays linear)
  int aOff[4], gOff[4], ldsO[4];
#pragma unroll
  for (int i = 0; i < 4; ++i) {
    int q = i * 256 + tid;               // 1024 chunks of 16B = 128x64 bf16
    int r = q >> 3, c = q & 7, lc = c ^ (r & 7);
    int arow = routed ? tokmap[row0 + r] : (row0 + r);
    aOff[i] = arow * 1024 + lc * 8;
    gOff[i] = (colG + r) * 1024 + lc * 8;
    ldsO[i] = (i * 256 + (tid & ~63)) * 8;
  }

  f32x4 accG[4][4] = {};
  f32x4 accU[4][4] = {};
  for (int k0 = 0; k0 < 1024; k0 += 64) {
    if (k0) __syncthreads();
#pragma unroll
    for (int i = 0; i < 4; ++i) gll16(Xb + aOff[i] + k0, lA + ldsO[i] + lane * 8);
#pragma unroll
    for (int i = 0; i < 4; ++i) gll16(GT + gOff[i] + k0, lG + ldsO[i] + lane * 8);
#pragma unroll
    for (int i = 0; i < 4; ++i) gll16(UT + gOff[i] + k0, lU + ldsO[i] + lane * 8);
    __syncthreads();
#pragma unroll
    for (int kc = 0; kc < 2; ++kc) {
      const int clog = kc * 4 + (lane >> 4);
      s16x8 af[4], gf[4], uf[4];
#pragma unroll
      for (int fr = 0; fr < 4; ++fr) {
        int rl = wr + fr * 16 + (lane & 15);
        af[fr] = *(const s16x8*)&lA[rl * 64 + ((clog ^ (rl & 7)) << 3)];
      }
#pragma unroll
      for (int cf = 0; cf < 4; ++cf) {
        int cl = wc + cf * 16 + (lane & 15);
        int off = cl * 64 + ((clog ^ (cl & 7)) << 3);
        gf[cf] = *(const s16x8*)&lG[off];
        uf[cf] = *(const s16x8*)&lU[off];
      }
#pragma unroll
      for (int fr = 0; fr < 4; ++fr)
#pragma unroll
        for (int cf = 0; cf < 4; ++cf) {
          accG[fr][cf] = mfma_bf16(af[fr], gf[cf], accG[fr][cf]);
          accU[fr][cf] = mfma_bf16(af[fr], uf[cf], accU[fr][cf]);
        }
    }
  }
#pragma unroll
  for (int fr = 0; fr < 4; ++fr)
#pragma unroll
    for (int r = 0; r < 4; ++r) {
      const int row = row0 + wr + fr * 16 + ((lane >> 4) << 2) + r;
      const float sc = routed ? rowscale[row] : scales[row * 4 + 2];
#pragma unroll
      for (int cf = 0; cf < 4; ++cf) {
        const int col = col0 + wc + cf * 16 + (lane & 15);
        float g = accG[fr][cf][r];
        float u = accU[fr][cf][r];
        float a = 0.5f * g * (1.0f + erff(g * 0.70710678118654752f));
        Out[(size_t)row * outLd + col] = f2b(a * u * sc);
      }
    }
}

// ---------------- GEMM2: down-projection, 128x128 tiles (m97 shape) ----------
// ROUTED: out_r[row][h] = Bg[row] @ down_e  (bf16), K=512.  grid (8, 72)
// SHARED: out[t][h] = Bs[t] @ down_s + out_r[r0][h] + out_r[r1][h] (f32). (8,32)
template<int ROUTED>
__global__ __launch_bounds__(256) void gemm2_k(
    const ushort* __restrict__ A, const ushort* __restrict__ DT,
    const int* __restrict__ meta, const int* __restrict__ tokrows,
    const ushort* __restrict__ Rrows, ushort* __restrict__ OutB,
    float* __restrict__ OutF)
{
  __shared__ __align__(16) ushort lA[128 * 64];
  __shared__ __align__(16) ushort lB[128 * 64];
  int e = 0;
  if (ROUTED) {
    if ((int)blockIdx.y >= meta[127]) return;
    e = meta[blockIdx.y];
  }
  const int K = ROUTED ? 512 : 1024;
  const int bBase = ROUTED ? e * 512 : 4096;
  const int tid = threadIdx.x, wid = tid >> 6, lane = tid & 63;
  const int col0 = blockIdx.x * 128, row0 = blockIdx.y * 128;
  const int wr = (wid >> 1) * 64, wc = (wid & 1) * 64;

  int aOff[4], bOff[4], lds[4];
#pragma unroll
  for (int i = 0; i < 4; ++i) {
    int q = i * 256 + tid;
    int r = q >> 3, c = q & 7, lc = c ^ (r & 7);
    aOff[i] = (row0 + r) * K + lc * 8;
    bOff[i] = (col0 + r) * 5120 + bBase + lc * 8;
    lds[i]  = (i * 256 + (tid & ~63)) * 8;
  }
  f32x4 acc[4][4] = {};
  for (int k0 = 0; k0 < K; k0 += 64) {
    if (k0) __syncthreads();
#pragma unroll
    for (int i = 0; i < 4; ++i) gll16(A + aOff[i] + k0, lA + lds[i] + lane * 8);
#pragma unroll
    for (int i = 0; i < 4; ++i) gll16(DT + bOff[i] + k0, lB + lds[i] + lane * 8);
    __syncthreads();
#pragma unroll
    for (int kc = 0; kc < 2; ++kc) {
      const int clog = kc * 4 + (lane >> 4);
      s16x8 af[4], bf[4];
#pragma unroll
      for (int fr = 0; fr < 4; ++fr) {
        int rl = wr + fr * 16 + (lane & 15);
        af[fr] = *(const s16x8*)&lA[rl * 64 + ((clog ^ (rl & 7)) << 3)];
      }
#pragma unroll
      for (int cf = 0; cf < 4; ++cf) {
        int cl = wc + cf * 16 + (lane & 15);
        bf[cf] = *(const s16x8*)&lB[cl * 64 + ((clog ^ (cl & 7)) << 3)];
      }
#pragma unroll
      for (int fr = 0; fr < 4; ++fr)
#pragma unroll
        for (int cf = 0; cf < 4; ++cf)
          acc[fr][cf] = mfma_bf16(af[fr], bf[cf], acc[fr][cf]);
    }
  }
#pragma unroll
  for (int fr = 0; fr < 4; ++fr)
#pragma unroll
    for (int r = 0; r < 4; ++r) {
      const int row = row0 + wr + fr * 16 + ((lane >> 4) << 2) + r;
      if (ROUTED) {
#pragma unroll
        for (int cf = 0; cf < 4; ++cf) {
          const int col = col0 + wc + cf * 16 + (lane & 15);
          OutB[row * 1024 + col] = f2b(acc[fr][cf][r]);
        }
      } else {
        const int r0 = tokrows[row * 2], r1 = tokrows[row * 2 + 1];
#pragma unroll
        for (int cf = 0; cf < 4; ++cf) {
          const int col = col0 + wc + cf * 16 + (lane & 15);
          float v = acc[fr][cf][r]
                  + b2f(Rrows[r0 * 1024 + col]) + b2f(Rrows[r1 * 1024 + col]);
          OutF[row * 1024 + col] = v;
        }
      }
    }
}

extern "C" void kernel_launch(void* const* d_in, const int* in_sizes, int n_in,
                              void* d_out, int out_size, void* d_ws, size_t ws_size,
                              hipStream_t stream) {
  const float* X    = (const float*)d_in[0];   // [4096,1024]
  const int*   task = (const int*)  d_in[1];
  const float* Gw   = (const float*)d_in[2];   // [8,1024]
  const float* Temb = (const float*)d_in[3];   // [3,1024]
  const float* Weg  = (const float*)d_in[4];   // [8,1024,512]
  const float* Weu  = (const float*)d_in[5];   // [8,1024,512]
  const float* Wed  = (const float*)d_in[6];   // [8,512,1024]
  const float* Wsg  = (const float*)d_in[7];   // [1024,1024]
  const float* Wsu  = (const float*)d_in[8];   // [1024,1024]
  const float* Wsd  = (const float*)d_in[9];   // [1024,1024]
  const float* Wc   = (const float*)d_in[10];  // [1024,2]

  char* ws = (char*)d_ws;
  float*  scales   = (float*)(ws + 0x00000);        // 4096*4 f32
  int*    topk     = (int*)  (ws + 0x10000);        // 4096*2
  int*    tokmap   = (int*)  (ws + 0x18000);        // <=9208
  int*    tokrows  = (int*)  (ws + 0x22000);        // 4096*2
  float*  rowscale = (float*)(ws + 0x2A000);        // <=9208
  int*    meta     = (int*)  (ws + 0x34000);        // 128
  ushort* Xb       = (ushort*)(ws + 0x40000);       // 4096*1024
  ushort* GT       = Xb + 4096 * 1024;              // 5120*1024
  ushort* UT       = GT + 5120 * 1024;
  ushort* DT       = UT + 5120 * 1024;              // 1024*5120
  ushort* Bg       = DT + 1024 * 5120;              // 9216*512
  ushort* Bs       = Bg + 9216 * 512;               // 4096*1024
  ushort* out_r    = Bs + 4096 * 1024;              // 9216*1024

  transpose_k<0><<<dim3(16, 32, 16), 256, 0, stream>>>(Weg, Weu, nullptr, GT, UT, nullptr);
  transpose_k<1><<<dim3(32, 16, 8), 256, 0, stream>>>(Wed, nullptr, nullptr, DT, nullptr, nullptr);
  transpose_k<2><<<dim3(32, 32, 3), 256, 0, stream>>>(
      Wsg, Wsu, Wsd, GT + 4096 * 1024, UT + 4096 * 1024, DT + 4096);

  router_k<<<1024, 256, 0, stream>>>(X, Gw, Temb, task, Wc, scales, topk, Xb);
  indexbuild_k<<<1, 256, 0, stream>>>(topk, scales, tokmap, tokrows, rowscale, meta);

  gemm1_k<<<dim3(8, 104), 256, 0, stream>>>(Xb, GT, UT, scales, tokmap, rowscale, meta, Bg, Bs);

  gemm2_k<1><<<dim3(8, 72), 256, 0, stream>>>(Bg, DT, meta, tokrows, (const ushort*)nullptr, out_r, (float*)nullptr);
  gemm2_k<0><<<dim3(8, 32), 256, 0, stream>>>(Bs, DT, meta, tokrows, out_r, (ushort*)nullptr, (float*)d_out);
}

// Round 8
// 188.583 us; speedup vs baseline: 1.3195x; 1.3195x over previous
//
#include <hip/hip_runtime.h>
#include <hip/hip_bf16.h>

// DeepseekMoE fused, top-2 SPARSE routed experts.
// r8: 1-deep software pipeline (T3-minimum) in all GEMMs: per K-step
//   { STAGE(next tile, other buffer) -> compute(cur) -> vmcnt(0) -> s_barrier }
// One barrier + one drain per K-step; HBM latency hides under compute.
// gemm1: 64x64 tiles (r6 shape, 44 VGPR) + dbuf (48KB, 3 blocks/CU).
// gemm2: 128x128 m97 shape + dbuf (64KB, 2 blocks/CU; queued <=2.25 anyway).
// Buckets 128-aligned; gemm1 routed rows = 64-row slices (expert=meta[y>>1]).
// T=4096, H=1024, E=8, I=512, IS=1024.

typedef short  s16x8 __attribute__((ext_vector_type(8)));
typedef __bf16 bf16x8 __attribute__((ext_vector_type(8)));
typedef float  f32x4 __attribute__((ext_vector_type(4)));

__device__ __forceinline__ float b2f(ushort u) {
  union { unsigned int i; float f; } v; v.i = ((unsigned int)u) << 16; return v.f;
}
__device__ __forceinline__ ushort f2b(float f) {
  union { float f; unsigned int i; } v; v.f = f;
  unsigned int r = v.i + 0x7fffu + ((v.i >> 16) & 1u);
  return (ushort)(r >> 16);
}
__device__ __forceinline__ f32x4 mfma_bf16(s16x8 a, s16x8 b, f32x4 c) {
  return __builtin_amdgcn_mfma_f32_16x16x32_bf16(
      __builtin_bit_cast(bf16x8, a), __builtin_bit_cast(bf16x8, b), c, 0, 0, 0);
}
__device__ __forceinline__ void gll16(const ushort* g, const ushort* l) {
  __builtin_amdgcn_global_load_lds(
      (const __attribute__((address_space(1))) unsigned int*)g,
      (__attribute__((address_space(3))) unsigned int*)l, 16, 0, 0);
}

// -------- tiled transpose + cast, 3 tight-grid variants ----------------------
template<int MODE>
__global__ __launch_bounds__(256) void transpose_k(
    const float* __restrict__ S0, const float* __restrict__ S1,
    const float* __restrict__ S2, ushort* __restrict__ D0,
    ushort* __restrict__ D1, ushort* __restrict__ D2)
{
  const int z = blockIdx.z;
  const float* src; ushort* dst; int srcLd, dstLd;
  if (MODE == 0) {
    src = (z < 8 ? S0 + (size_t)z * 512 * 1024 : S1 + (size_t)(z - 8) * 512 * 1024);
    dst = (z < 8 ? D0 + (size_t)z * 512 * 1024 : D1 + (size_t)(z - 8) * 512 * 1024);
    srcLd = 512; dstLd = 1024;
  } else if (MODE == 1) {
    src = S0 + (size_t)z * 512 * 1024; dst = D0 + (size_t)z * 512;
    srcLd = 1024; dstLd = 5120;
  } else {
    src = (z == 0 ? S0 : z == 1 ? S1 : S2);
    dst = (z == 0 ? D0 : z == 1 ? D1 : D2);
    srcLd = 1024; dstLd = (z == 2 ? 5120 : 1024);
  }
  __shared__ float tile[32][33];
  const int c0 = blockIdx.x * 32, r0 = blockIdx.y * 32;
  const int tx = threadIdx.x & 31, ty = threadIdx.x >> 5;
#pragma unroll
  for (int j = 0; j < 4; ++j)
    tile[ty + j * 8][tx] = src[(size_t)(r0 + ty + j * 8) * srcLd + c0 + tx];
  __syncthreads();
#pragma unroll
  for (int j = 0; j < 4; ++j)
    dst[(size_t)(c0 + ty + j * 8) * dstLd + r0 + tx] = f2b(tile[tx][ty + j * 8]);
}

// ---------------- router (f32) + X->bf16 cast --------------------------------
__global__ __launch_bounds__(256) void router_k(
    const float* __restrict__ X, const float* __restrict__ Gw,
    const float* __restrict__ Temb, const int* __restrict__ task_id,
    const float* __restrict__ Wc, float* __restrict__ scales,
    int* __restrict__ topk, ushort* __restrict__ Xb)
{
  const int wid = threadIdx.x >> 6, lane = threadIdx.x & 63;
  const int t = blockIdx.x * 4 + wid;
  const float* xr = X + t * 1024;
  const float* er = Temb + task_id[0] * 1024;

  float x[16], xe[16];
#pragma unroll
  for (int c = 0; c < 4; ++c) {
    float4 v = *(const float4*)&xr[c * 256 + lane * 4];
    float4 e = *(const float4*)&er[c * 256 + lane * 4];
    x[c * 4 + 0] = v.x; x[c * 4 + 1] = v.y; x[c * 4 + 2] = v.z; x[c * 4 + 3] = v.w;
    xe[c * 4 + 0] = v.x + e.x; xe[c * 4 + 1] = v.y + e.y;
    xe[c * 4 + 2] = v.z + e.z; xe[c * 4 + 3] = v.w + e.w;
  }
#pragma unroll
  for (int c = 0; c < 4; ++c) {
    ushort4 o;
    o.x = f2b(x[c * 4 + 0]); o.y = f2b(x[c * 4 + 1]);
    o.z = f2b(x[c * 4 + 2]); o.w = f2b(x[c * 4 + 3]);
    *(ushort4*)&Xb[t * 1024 + c * 256 + lane * 4] = o;
  }
  float logit[8];
#pragma unroll
  for (int e = 0; e < 8; ++e) {
    float p = 0.f;
#pragma unroll
    for (int c = 0; c < 4; ++c) {
      float4 g = *(const float4*)&Gw[e * 1024 + c * 256 + lane * 4];
      p += xe[c * 4] * g.x + xe[c * 4 + 1] * g.y + xe[c * 4 + 2] * g.z + xe[c * 4 + 3] * g.w;
    }
#pragma unroll
    for (int off = 32; off; off >>= 1) p += __shfl_xor(p, off);
    logit[e] = p;
  }
  float m = logit[0];
#pragma unroll
  for (int e = 1; e < 8; ++e) m = fmaxf(m, logit[e]);
  float pr[8], s = 0.f;
#pragma unroll
  for (int e = 0; e < 8; ++e) { pr[e] = expf(logit[e] - m); s += pr[e]; }
  float inv = 1.f / s;
#pragma unroll
  for (int e = 0; e < 8; ++e) pr[e] *= inv;
  int i1 = 0; float m1 = pr[0];
#pragma unroll
  for (int e = 1; e < 8; ++e) if (pr[e] > m1) { m1 = pr[e]; i1 = e; }
  int i2 = -1; float m2 = -1.f;
#pragma unroll
  for (int e = 0; e < 8; ++e) if (e != i1 && pr[e] > m2) { m2 = pr[e]; i2 = e; }
  float dn = 1.f / (m1 + m2 + 1e-20f);
  float w1 = m1 * dn, w2 = m2 * dn;

  float a0 = 0.f, a1 = 0.f;
#pragma unroll
  for (int c = 0; c < 4; ++c)
#pragma unroll
    for (int j = 0; j < 4; ++j) {
      int h = c * 256 + lane * 4 + j;
      a0 += x[c * 4 + j] * Wc[h * 2];
      a1 += x[c * 4 + j] * Wc[h * 2 + 1];
    }
#pragma unroll
  for (int off = 32; off; off >>= 1) {
    a0 += __shfl_xor(a0, off); a1 += __shfl_xor(a1, off);
  }
  float am = fmaxf(a0, a1);
  float ea0 = expf(a0 - am), ea1 = expf(a1 - am);
  float al0 = ea0 / (ea0 + ea1), al1 = ea1 / (ea0 + ea1);

  if (lane == 0) {
    scales[t * 4 + 0] = al0 * w1;
    scales[t * 4 + 1] = al0 * w2;
    scales[t * 4 + 2] = al1;
    topk[t * 2 + 0] = i1;
    topk[t * 2 + 1] = i2;
  }
}

// ---------------- index build: per-expert 128-aligned token buckets ----------
// meta[0..71] = 128-row block -> expert; meta[127] = total 128-row blocks.
__global__ __launch_bounds__(256) void indexbuild_k(
    const int* __restrict__ topk, const float* __restrict__ scales,
    int* __restrict__ tokmap, int* __restrict__ tokrows,
    float* __restrict__ rowscale, int* __restrict__ meta)
{
  __shared__ int cnt[8], cnt2[8], base[8];
  const int tid = threadIdx.x;
  if (tid < 8) { cnt[tid] = 0; cnt2[tid] = 0; }
  __syncthreads();
  for (int t = tid; t < 4096; t += 256) {
    atomicAdd(&cnt[topk[t * 2]], 1);
    atomicAdd(&cnt[topk[t * 2 + 1]], 1);
  }
  __syncthreads();
  if (tid == 0) {
    int nb = 0;
    for (int e = 0; e < 8; ++e) {
      base[e] = nb * 128;
      int blocks = (cnt[e] + 127) >> 7;
      for (int j = 0; j < blocks; ++j) meta[nb + j] = e;
      nb += blocks;
    }
    meta[127] = nb;
  }
  __syncthreads();
  for (int t = tid; t < 4096; t += 256) {
#pragma unroll
    for (int r = 0; r < 2; ++r) {
      int e = topk[t * 2 + r];
      int slot = atomicAdd(&cnt2[e], 1);
      int row = base[e] + slot;
      tokmap[row] = t;
      rowscale[row] = scales[t * 4 + r];
      tokrows[t * 2 + r] = row;
    }
  }
  __syncthreads();
  for (int e = 0; e < 8; ++e) {
    int c = cnt[e], R = ((c + 127) >> 7) << 7;
    for (int j = c + tid; j < R; j += 256) {
      tokmap[base[e] + j] = 0;
      rowscale[base[e] + j] = 0.f;
    }
  }
}

// ------- MERGED GEMM1: routed + shared gate/up, 64x64 tiles, pipelined -------
// grid (16, 208). y<144: routed 64-row slice (x<8, (y>>1)<meta[127]),
//                 y>=144: shared token block (all 16 x).
// 4 waves (2x2 of 32x32), dual G/U acc (16 f32x4). dbuf LDS 48KB.
__global__ __launch_bounds__(256) void gemm1_k(
    const ushort* __restrict__ Xb, const ushort* __restrict__ GT,
    const ushort* __restrict__ UT, const float* __restrict__ scales,
    const int* __restrict__ tokmap, const float* __restrict__ rowscale,
    const int* __restrict__ meta, ushort* __restrict__ Bg,
    ushort* __restrict__ Bs)
{
  __shared__ __align__(16) ushort lA[2][64 * 64];
  __shared__ __align__(16) ushort lG[2][64 * 64];
  __shared__ __align__(16) ushort lU[2][64 * 64];
  const int x = blockIdx.x, y = blockIdx.y;
  const bool routed = y < 144;
  if (routed && (x >= 8 || (y >> 1) >= meta[127])) return;

  const int tid = threadIdx.x, wid = tid >> 6, lane = tid & 63;
  const int col0 = x * 64;
  const int row0 = routed ? y * 64 : (y - 144) * 64;
  const int colG = routed ? (meta[y >> 1] * 512 + col0) : (4096 + col0);
  const int wr = (wid >> 1) * 32, wc = (wid & 1) * 32;
  ushort* __restrict__ Out = routed ? Bg : Bs;
  const int outLd = routed ? 512 : 1024;

  // staging: physical 16B chunk (r,c) holds logical chunk c^(r&7) (XOR swizzle
  // on the GLOBAL source address; LDS destination stays linear)
  int aOff[2], gOff[2], ldsO[2];
#pragma unroll
  for (int i = 0; i < 2; ++i) {
    int q = i * 256 + tid;               // 512 chunks of 16B = 64x64 bf16 tile
    int r = q >> 3, c = q & 7, lc = c ^ (r & 7);
    int arow = routed ? tokmap[row0 + r] : (row0 + r);
    aOff[i] = arow * 1024 + lc * 8;
    gOff[i] = (colG + r) * 1024 + lc * 8;
    ldsO[i] = (i * 256 + (tid & ~63)) * 8 + lane * 8;
  }

  f32x4 accG[2][2] = {};
  f32x4 accU[2][2] = {};

  // prologue: stage tile 0 into buffer 0
#pragma unroll
  for (int i = 0; i < 2; ++i) gll16(Xb + aOff[i], lA[0] + ldsO[i]);
#pragma unroll
  for (int i = 0; i < 2; ++i) gll16(GT + gOff[i], lG[0] + ldsO[i]);
#pragma unroll
  for (int i = 0; i < 2; ++i) gll16(UT + gOff[i], lU[0] + ldsO[i]);
  asm volatile("s_waitcnt vmcnt(0)" ::: "memory");
  __builtin_amdgcn_s_barrier();

  for (int t = 0; t < 16; ++t) {
    const int cur = t & 1, nxt = cur ^ 1;
    if (t < 15) {
      const int k0 = (t + 1) * 64;
#pragma unroll
      for (int i = 0; i < 2; ++i) gll16(Xb + aOff[i] + k0, lA[nxt] + ldsO[i]);
#pragma unroll
      for (int i = 0; i < 2; ++i) gll16(GT + gOff[i] + k0, lG[nxt] + ldsO[i]);
#pragma unroll
      for (int i = 0; i < 2; ++i) gll16(UT + gOff[i] + k0, lU[nxt] + ldsO[i]);
    }
#pragma unroll
    for (int kc = 0; kc < 2; ++kc) {
      const int clog = kc * 4 + (lane >> 4);
      s16x8 af[2], gf[2], uf[2];
#pragma unroll
      for (int fr = 0; fr < 2; ++fr) {
        int rl = wr + fr * 16 + (lane & 15);
        af[fr] = *(const s16x8*)&lA[cur][rl * 64 + ((clog ^ (rl & 7)) << 3)];
      }
#pragma unroll
      for (int cf = 0; cf < 2; ++cf) {
        int cl = wc + cf * 16 + (lane & 15);
        int off = cl * 64 + ((clog ^ (cl & 7)) << 3);
        gf[cf] = *(const s16x8*)&lG[cur][off];
        uf[cf] = *(const s16x8*)&lU[cur][off];
      }
#pragma unroll
      for (int fr = 0; fr < 2; ++fr)
#pragma unroll
        for (int cf = 0; cf < 2; ++cf) {
          accG[fr][cf] = mfma_bf16(af[fr], gf[cf], accG[fr][cf]);
          accU[fr][cf] = mfma_bf16(af[fr], uf[cf], accU[fr][cf]);
        }
    }
    asm volatile("s_waitcnt vmcnt(0)" ::: "memory");
    __builtin_amdgcn_s_barrier();
  }

#pragma unroll
  for (int fr = 0; fr < 2; ++fr)
#pragma unroll
    for (int r = 0; r < 4; ++r) {
      const int row = row0 + wr + fr * 16 + ((lane >> 4) << 2) + r;
      const float sc = routed ? rowscale[row] : scales[row * 4 + 2];
#pragma unroll
      for (int cf = 0; cf < 2; ++cf) {
        const int col = col0 + wc + cf * 16 + (lane & 15);
        float g = accG[fr][cf][r];
        float u = accU[fr][cf][r];
        float a = 0.5f * g * (1.0f + erff(g * 0.70710678118654752f));
        Out[(size_t)row * outLd + col] = f2b(a * u * sc);
      }
    }
}

// ------- GEMM2: down-projection, 128x128 m97 shape, pipelined ----------------
// ROUTED: out_r[row][h] = Bg[row] @ down_e  (bf16), K=512.  grid (8, 72)
// SHARED: out[t][h] = Bs[t] @ down_s + out_r[r0][h] + out_r[r1][h] (f32). (8,32)
template<int ROUTED>
__global__ __launch_bounds__(256) void gemm2_k(
    const ushort* __restrict__ A, const ushort* __restrict__ DT,
    const int* __restrict__ meta, const int* __restrict__ tokrows,
    const ushort* __restrict__ Rrows, ushort* __restrict__ OutB,
    float* __restrict__ OutF)
{
  __shared__ __align__(16) ushort lA[2][128 * 64];
  __shared__ __align__(16) ushort lB[2][128 * 64];
  int e = 0;
  if (ROUTED) {
    if ((int)blockIdx.y >= meta[127]) return;
    e = meta[blockIdx.y];
  }
  const int K = ROUTED ? 512 : 1024;
  const int nsteps = K / 64;
  const int bBase = ROUTED ? e * 512 : 4096;
  const int tid = threadIdx.x, wid = tid >> 6, lane = tid & 63;
  const int col0 = blockIdx.x * 128, row0 = blockIdx.y * 128;
  const int wr = (wid >> 1) * 64, wc = (wid & 1) * 64;

  int aOff[4], bOff[4], lds[4];
#pragma unroll
  for (int i = 0; i < 4; ++i) {
    int q = i * 256 + tid;               // 1024 chunks of 16B = 128x64 bf16
    int r = q >> 3, c = q & 7, lc = c ^ (r & 7);
    aOff[i] = (row0 + r) * K + lc * 8;
    bOff[i] = (col0 + r) * 5120 + bBase + lc * 8;
    lds[i]  = (i * 256 + (tid & ~63)) * 8 + lane * 8;
  }
  f32x4 acc[4][4] = {};

  // prologue
#pragma unroll
  for (int i = 0; i < 4; ++i) gll16(A + aOff[i], lA[0] + lds[i]);
#pragma unroll
  for (int i = 0; i < 4; ++i) gll16(DT + bOff[i], lB[0] + lds[i]);
  asm volatile("s_waitcnt vmcnt(0)" ::: "memory");
  __builtin_amdgcn_s_barrier();

  for (int t = 0; t < nsteps; ++t) {
    const int cur = t & 1, nxt = cur ^ 1;
    if (t < nsteps - 1) {
      const int k0 = (t + 1) * 64;
#pragma unroll
      for (int i = 0; i < 4; ++i) gll16(A + aOff[i] + k0, lA[nxt] + lds[i]);
#pragma unroll
      for (int i = 0; i < 4; ++i) gll16(DT + bOff[i] + k0, lB[nxt] + lds[i]);
    }
#pragma unroll
    for (int kc = 0; kc < 2; ++kc) {
      const int clog = kc * 4 + (lane >> 4);
      s16x8 af[4], bf[4];
#pragma unroll
      for (int fr = 0; fr < 4; ++fr) {
        int rl = wr + fr * 16 + (lane & 15);
        af[fr] = *(const s16x8*)&lA[cur][rl * 64 + ((clog ^ (rl & 7)) << 3)];
      }
#pragma unroll
      for (int cf = 0; cf < 4; ++cf) {
        int cl = wc + cf * 16 + (lane & 15);
        bf[cf] = *(const s16x8*)&lB[cur][cl * 64 + ((clog ^ (cl & 7)) << 3)];
      }
#pragma unroll
      for (int fr = 0; fr < 4; ++fr)
#pragma unroll
        for (int cf = 0; cf < 4; ++cf)
          acc[fr][cf] = mfma_bf16(af[fr], bf[cf], acc[fr][cf]);
    }
    asm volatile("s_waitcnt vmcnt(0)" ::: "memory");
    __builtin_amdgcn_s_barrier();
  }

#pragma unroll
  for (int fr = 0; fr < 4; ++fr)
#pragma unroll
    for (int r = 0; r < 4; ++r) {
      const int row = row0 + wr + fr * 16 + ((lane >> 4) << 2) + r;
      if (ROUTED) {
#pragma unroll
        for (int cf = 0; cf < 4; ++cf) {
          const int col = col0 + wc + cf * 16 + (lane & 15);
          OutB[row * 1024 + col] = f2b(acc[fr][cf][r]);
        }
      } else {
        const int r0 = tokrows[row * 2], r1 = tokrows[row * 2 + 1];
#pragma unroll
        for (int cf = 0; cf < 4; ++cf) {
          const int col = col0 + wc + cf * 16 + (lane & 15);
          float v = acc[fr][cf][r]
                  + b2f(Rrows[r0 * 1024 + col]) + b2f(Rrows[r1 * 1024 + col]);
          OutF[row * 1024 + col] = v;
        }
      }
    }
}

extern "C" void kernel_launch(void* const* d_in, const int* in_sizes, int n_in,
                              void* d_out, int out_size, void* d_ws, size_t ws_size,
                              hipStream_t stream) {
  const float* X    = (const float*)d_in[0];   // [4096,1024]
  const int*   task = (const int*)  d_in[1];
  const float* Gw   = (const float*)d_in[2];   // [8,1024]
  const float* Temb = (const float*)d_in[3];   // [3,1024]
  const float* Weg  = (const float*)d_in[4];   // [8,1024,512]
  const float* Weu  = (const float*)d_in[5];   // [8,1024,512]
  const float* Wed  = (const float*)d_in[6];   // [8,512,1024]
  const float* Wsg  = (const float*)d_in[7];   // [1024,1024]
  const float* Wsu  = (const float*)d_in[8];   // [1024,1024]
  const float* Wsd  = (const float*)d_in[9];   // [1024,1024]
  const float* Wc   = (const float*)d_in[10];  // [1024,2]

  char* ws = (char*)d_ws;
  float*  scales   = (float*)(ws + 0x00000);        // 4096*4 f32
  int*    topk     = (int*)  (ws + 0x10000);        // 4096*2
  int*    tokmap   = (int*)  (ws + 0x18000);        // <=9216
  int*    tokrows  = (int*)  (ws + 0x22000);        // 4096*2
  float*  rowscale = (float*)(ws + 0x2A000);        // <=9216
  int*    meta     = (int*)  (ws + 0x34000);        // 128
  ushort* Xb       = (ushort*)(ws + 0x40000);       // 4096*1024
  ushort* GT       = Xb + 4096 * 1024;              // 5120*1024
  ushort* UT       = GT + 5120 * 1024;
  ushort* DT       = UT + 5120 * 1024;              // 1024*5120
  ushort* Bg       = DT + 1024 * 5120;              // 9216*512
  ushort* Bs       = Bg + 9216 * 512;               // 4096*1024
  ushort* out_r    = Bs + 4096 * 1024;              // 9216*1024

  transpose_k<0><<<dim3(16, 32, 16), 256, 0, stream>>>(Weg, Weu, nullptr, GT, UT, nullptr);
  transpose_k<1><<<dim3(32, 16, 8), 256, 0, stream>>>(Wed, nullptr, nullptr, DT, nullptr, nullptr);
  transpose_k<2><<<dim3(32, 32, 3), 256, 0, stream>>>(
      Wsg, Wsu, Wsd, GT + 4096 * 1024, UT + 4096 * 1024, DT + 4096);

  router_k<<<1024, 256, 0, stream>>>(X, Gw, Temb, task, Wc, scales, topk, Xb);
  indexbuild_k<<<1, 256, 0, stream>>>(topk, scales, tokmap, tokrows, rowscale, meta);

  gemm1_k<<<dim3(16, 208), 256, 0, stream>>>(Xb, GT, UT, scales, tokmap, rowscale, meta, Bg, Bs);

  gemm2_k<1><<<dim3(8, 72), 256, 0, stream>>>(Bg, DT, meta, tokrows, (const ushort*)nullptr, out_r, (float*)nullptr);
  gemm2_k<0><<<dim3(8, 32), 256, 0, stream>>>(Bs, DT, meta, tokrows, out_r, (ushort*)nullptr, (float*)d_out);
}

// Round 9
// 175.324 us; speedup vs baseline: 1.4193x; 1.0756x over previous
//
#include <hip/hip_runtime.h>
#include <hip/hip_bf16.h>

// DeepseekMoE fused, top-2 SPARSE routed experts. r9 = best measured pieces:
//   prep_k  : ALL weight transposes + router in ONE 16384-block dispatch
//   indexbuild_k : 128-aligned expert bases; 64-row slice table for gemm1,
//                  128-row block table for gemm2r
//   gemm1_k : r6's 64x64 single-buffer shape (78us measured; TLP > pipelining)
//   gemm2_k : r7's 128x128 m97 single-buffer shape (~23us pair measured)
// r5/r8 lesson: vmcnt-pipelined dbuf regresses here (drain stays serial,
// LDS doubling cuts residency). T=4096, H=1024, E=8, I=512, IS=1024.

typedef short  s16x8 __attribute__((ext_vector_type(8)));
typedef __bf16 bf16x8 __attribute__((ext_vector_type(8)));
typedef float  f32x4 __attribute__((ext_vector_type(4)));

__device__ __forceinline__ float b2f(ushort u) {
  union { unsigned int i; float f; } v; v.i = ((unsigned int)u) << 16; return v.f;
}
__device__ __forceinline__ ushort f2b(float f) {
  union { float f; unsigned int i; } v; v.f = f;
  unsigned int r = v.i + 0x7fffu + ((v.i >> 16) & 1u);
  return (ushort)(r >> 16);
}
__device__ __forceinline__ f32x4 mfma_bf16(s16x8 a, s16x8 b, f32x4 c) {
  return __builtin_amdgcn_mfma_f32_16x16x32_bf16(
      __builtin_bit_cast(bf16x8, a), __builtin_bit_cast(bf16x8, b), c, 0, 0, 0);
}
__device__ __forceinline__ void gll16(const ushort* g, const ushort* l) {
  __builtin_amdgcn_global_load_lds(
      (const __attribute__((address_space(1))) unsigned int*)g,
      (__attribute__((address_space(3))) unsigned int*)l, 16, 0, 0);
}

// ---------------- PREP: all transposes (+cast) AND router in one dispatch ----
// blocks [0,8192):   Weg/Weu -> GT/UT   (z=id>>9: z<8 gate, else up)
// blocks [8192,12288): Wed -> DT
// blocks [12288,15360): Wsg/Wsu/Wsd -> GT+4M / UT+4M / DT+4096
// blocks [15360,16384): router (1024 blocks x 4 tokens)
__global__ __launch_bounds__(256) void prep_k(
    const float* __restrict__ X, const float* __restrict__ Gw,
    const float* __restrict__ Temb, const int* __restrict__ task_id,
    const float* __restrict__ Wc,
    const float* __restrict__ Weg, const float* __restrict__ Weu,
    const float* __restrict__ Wed, const float* __restrict__ Wsg,
    const float* __restrict__ Wsu, const float* __restrict__ Wsd,
    ushort* __restrict__ GT, ushort* __restrict__ UT, ushort* __restrict__ DT,
    float* __restrict__ scales, int* __restrict__ topk,
    ushort* __restrict__ Xb)
{
  const int id = blockIdx.x;
  if (id < 15360) {
    // ---- transpose+cast: dst[c*dstLd + r] = bf16(src[r*srcLd + c]) ----
    const float* src; ushort* dst; int srcLd, dstLd, c0, r0;
    if (id < 8192) {
      int z = id >> 9, rem = id & 511;
      src = (z < 8 ? Weg + (size_t)z * 512 * 1024 : Weu + (size_t)(z - 8) * 512 * 1024);
      dst = (z < 8 ? GT + (size_t)z * 512 * 1024 : UT + (size_t)(z - 8) * 512 * 1024);
      srcLd = 512; dstLd = 1024;
      c0 = (rem & 15) * 32; r0 = (rem >> 4) * 32;
    } else if (id < 12288) {
      int id2 = id - 8192, z = id2 >> 9, rem = id2 & 511;
      src = Wed + (size_t)z * 512 * 1024; dst = DT + (size_t)z * 512;
      srcLd = 1024; dstLd = 5120;
      c0 = (rem & 31) * 32; r0 = (rem >> 5) * 32;
    } else {
      int id3 = id - 12288, z = id3 >> 10, rem = id3 & 1023;
      src = (z == 0 ? Wsg : z == 1 ? Wsu : Wsd);
      dst = (z == 0 ? GT + 4096 * 1024 : z == 1 ? UT + 4096 * 1024 : DT + 4096);
      srcLd = 1024; dstLd = (z == 2 ? 5120 : 1024);
      c0 = (rem & 31) * 32; r0 = (rem >> 5) * 32;
    }
    __shared__ float tile[32][33];
    const int tx = threadIdx.x & 31, ty = threadIdx.x >> 5;
#pragma unroll
    for (int j = 0; j < 4; ++j)
      tile[ty + j * 8][tx] = src[(size_t)(r0 + ty + j * 8) * srcLd + c0 + tx];
    __syncthreads();
#pragma unroll
    for (int j = 0; j < 4; ++j)
      dst[(size_t)(c0 + ty + j * 8) * dstLd + r0 + tx] = f2b(tile[tx][ty + j * 8]);
    return;
  }

  // ---- router (f32) + X->bf16 cast ----
  const int rid = id - 15360;
  const int wid = threadIdx.x >> 6, lane = threadIdx.x & 63;
  const int t = rid * 4 + wid;
  const float* xr = X + t * 1024;
  const float* er = Temb + task_id[0] * 1024;

  float x[16], xe[16];
#pragma unroll
  for (int c = 0; c < 4; ++c) {
    float4 v = *(const float4*)&xr[c * 256 + lane * 4];
    float4 e = *(const float4*)&er[c * 256 + lane * 4];
    x[c * 4 + 0] = v.x; x[c * 4 + 1] = v.y; x[c * 4 + 2] = v.z; x[c * 4 + 3] = v.w;
    xe[c * 4 + 0] = v.x + e.x; xe[c * 4 + 1] = v.y + e.y;
    xe[c * 4 + 2] = v.z + e.z; xe[c * 4 + 3] = v.w + e.w;
  }
#pragma unroll
  for (int c = 0; c < 4; ++c) {
    ushort4 o;
    o.x = f2b(x[c * 4 + 0]); o.y = f2b(x[c * 4 + 1]);
    o.z = f2b(x[c * 4 + 2]); o.w = f2b(x[c * 4 + 3]);
    *(ushort4*)&Xb[t * 1024 + c * 256 + lane * 4] = o;
  }
  float logit[8];
#pragma unroll
  for (int e = 0; e < 8; ++e) {
    float p = 0.f;
#pragma unroll
    for (int c = 0; c < 4; ++c) {
      float4 g = *(const float4*)&Gw[e * 1024 + c * 256 + lane * 4];
      p += xe[c * 4] * g.x + xe[c * 4 + 1] * g.y + xe[c * 4 + 2] * g.z + xe[c * 4 + 3] * g.w;
    }
#pragma unroll
    for (int off = 32; off; off >>= 1) p += __shfl_xor(p, off);
    logit[e] = p;
  }
  float m = logit[0];
#pragma unroll
  for (int e = 1; e < 8; ++e) m = fmaxf(m, logit[e]);
  float pr[8], s = 0.f;
#pragma unroll
  for (int e = 0; e < 8; ++e) { pr[e] = expf(logit[e] - m); s += pr[e]; }
  float inv = 1.f / s;
#pragma unroll
  for (int e = 0; e < 8; ++e) pr[e] *= inv;
  int i1 = 0; float m1 = pr[0];
#pragma unroll
  for (int e = 1; e < 8; ++e) if (pr[e] > m1) { m1 = pr[e]; i1 = e; }
  int i2 = -1; float m2 = -1.f;
#pragma unroll
  for (int e = 0; e < 8; ++e) if (e != i1 && pr[e] > m2) { m2 = pr[e]; i2 = e; }
  float dn = 1.f / (m1 + m2 + 1e-20f);
  float w1 = m1 * dn, w2 = m2 * dn;

  float a0 = 0.f, a1 = 0.f;
#pragma unroll
  for (int c = 0; c < 4; ++c)
#pragma unroll
    for (int j = 0; j < 4; ++j) {
      int h = c * 256 + lane * 4 + j;
      a0 += x[c * 4 + j] * Wc[h * 2];
      a1 += x[c * 4 + j] * Wc[h * 2 + 1];
    }
#pragma unroll
  for (int off = 32; off; off >>= 1) {
    a0 += __shfl_xor(a0, off); a1 += __shfl_xor(a1, off);
  }
  float am = fmaxf(a0, a1);
  float ea0 = expf(a0 - am), ea1 = expf(a1 - am);
  float al0 = ea0 / (ea0 + ea1), al1 = ea1 / (ea0 + ea1);

  if (lane == 0) {
    scales[t * 4 + 0] = al0 * w1;
    scales[t * 4 + 1] = al0 * w2;
    scales[t * 4 + 2] = al1;
    topk[t * 2 + 0] = i1;
    topk[t * 2 + 1] = i2;
  }
}

// ---------------- index build: 128-aligned expert bases ----------------------
// meta[0..143]   = expert of 64-row slice y  (gemm1)
// meta[160..303] = row0 of 64-row slice y    (gemm1)
// meta[320..391] = expert of 128-row block y (gemm2r)
// meta[510] = n 64-slices; meta[511] = n 128-blocks.
__global__ __launch_bounds__(256) void indexbuild_k(
    const int* __restrict__ topk, const float* __restrict__ scales,
    int* __restrict__ tokmap, int* __restrict__ tokrows,
    float* __restrict__ rowscale, int* __restrict__ meta)
{
  __shared__ int cnt[8], cnt2[8], base[8];
  const int tid = threadIdx.x;
  if (tid < 8) { cnt[tid] = 0; cnt2[tid] = 0; }
  __syncthreads();
  for (int t = tid; t < 4096; t += 256) {
    atomicAdd(&cnt[topk[t * 2]], 1);
    atomicAdd(&cnt[topk[t * 2 + 1]], 1);
  }
  __syncthreads();
  if (tid == 0) {
    int nb128 = 0, nb64 = 0;
    for (int e = 0; e < 8; ++e) {
      base[e] = nb128 * 128;
      int b128 = (cnt[e] + 127) >> 7;
      for (int j = 0; j < b128; ++j) meta[320 + nb128 + j] = e;
      int b64 = (cnt[e] + 63) >> 6;
      for (int j = 0; j < b64; ++j) {
        meta[nb64 + j] = e;
        meta[160 + nb64 + j] = base[e] + j * 64;
      }
      nb128 += b128; nb64 += b64;
    }
    meta[510] = nb64; meta[511] = nb128;
  }
  __syncthreads();
  for (int t = tid; t < 4096; t += 256) {
#pragma unroll
    for (int r = 0; r < 2; ++r) {
      int e = topk[t * 2 + r];
      int slot = atomicAdd(&cnt2[e], 1);
      int row = base[e] + slot;
      tokmap[row] = t;
      rowscale[row] = scales[t * 4 + r];
      tokrows[t * 2 + r] = row;
    }
  }
  __syncthreads();
  // pad to 64-ceiling (rows gemm1 writes); beyond that is never consumed
  for (int e = 0; e < 8; ++e) {
    int c = cnt[e], R = ((c + 63) >> 6) << 6;
    for (int j = c + tid; j < R; j += 256) {
      tokmap[base[e] + j] = 0;
      rowscale[base[e] + j] = 0.f;
    }
  }
}

// ------- MERGED GEMM1: routed + shared gate/up, 64x64 tiles (r6 shape) -------
// grid (16, 208). y<144: routed 64-row slice (x<8, y<meta[510]),
//                 y>=144: shared token block (all 16 x).
// 4 waves (2x2 of 32x32), dual G/U acc. LDS 24KB, single-buffered.
__global__ __launch_bounds__(256) void gemm1_k(
    const ushort* __restrict__ Xb, const ushort* __restrict__ GT,
    const ushort* __restrict__ UT, const float* __restrict__ scales,
    const int* __restrict__ tokmap, const float* __restrict__ rowscale,
    const int* __restrict__ meta, ushort* __restrict__ Bg,
    ushort* __restrict__ Bs)
{
  __shared__ __align__(16) ushort lA[64 * 64];
  __shared__ __align__(16) ushort lG[64 * 64];
  __shared__ __align__(16) ushort lU[64 * 64];
  const int x = blockIdx.x, y = blockIdx.y;
  const bool routed = y < 144;
  if (routed && (x >= 8 || y >= meta[510])) return;

  const int tid = threadIdx.x, wid = tid >> 6, lane = tid & 63;
  const int col0 = x * 64;
  const int row0 = routed ? meta[160 + y] : (y - 144) * 64;
  const int colG = routed ? (meta[y] * 512 + col0) : (4096 + col0);
  const int wr = (wid >> 1) * 32, wc = (wid & 1) * 32;
  ushort* __restrict__ Out = routed ? Bg : Bs;
  const int outLd = routed ? 512 : 1024;

  // staging: physical 16B chunk (r,c) holds logical chunk c^(r&7) (XOR swizzle
  // on the GLOBAL source address; LDS destination stays linear)
  int aOff[2], gOff[2], ldsO[2];
#pragma unroll
  for (int i = 0; i < 2; ++i) {
    int q = i * 256 + tid;               // 512 chunks of 16B = 64x64 bf16 tile
    int r = q >> 3, c = q & 7, lc = c ^ (r & 7);
    int arow = routed ? tokmap[row0 + r] : (row0 + r);
    aOff[i] = arow * 1024 + lc * 8;
    gOff[i] = (colG + r) * 1024 + lc * 8;
    ldsO[i] = (i * 256 + (tid & ~63)) * 8;
  }

  f32x4 accG[2][2] = {};
  f32x4 accU[2][2] = {};
  for (int k0 = 0; k0 < 1024; k0 += 64) {
    if (k0) __syncthreads();
#pragma unroll
    for (int i = 0; i < 2; ++i) gll16(Xb + aOff[i] + k0, lA + ldsO[i]);
#pragma unroll
    for (int i = 0; i < 2; ++i) gll16(GT + gOff[i] + k0, lG + ldsO[i]);
#pragma unroll
    for (int i = 0; i < 2; ++i) gll16(UT + gOff[i] + k0, lU + ldsO[i]);
    __syncthreads();
#pragma unroll
    for (int kc = 0; kc < 2; ++kc) {
      const int clog = kc * 4 + (lane >> 4);
      s16x8 af[2], gf[2], uf[2];
#pragma unroll
      for (int fr = 0; fr < 2; ++fr) {
        int rl = wr + fr * 16 + (lane & 15);
        af[fr] = *(const s16x8*)&lA[rl * 64 + ((clog ^ (rl & 7)) << 3)];
      }
#pragma unroll
      for (int cf = 0; cf < 2; ++cf) {
        int cl = wc + cf * 16 + (lane & 15);
        int off = cl * 64 + ((clog ^ (cl & 7)) << 3);
        gf[cf] = *(const s16x8*)&lG[off];
        uf[cf] = *(const s16x8*)&lU[off];
      }
#pragma unroll
      for (int fr = 0; fr < 2; ++fr)
#pragma unroll
        for (int cf = 0; cf < 2; ++cf) {
          accG[fr][cf] = mfma_bf16(af[fr], gf[cf], accG[fr][cf]);
          accU[fr][cf] = mfma_bf16(af[fr], uf[cf], accU[fr][cf]);
        }
    }
  }
#pragma unroll
  for (int fr = 0; fr < 2; ++fr)
#pragma unroll
    for (int r = 0; r < 4; ++r) {
      const int row = row0 + wr + fr * 16 + ((lane >> 4) << 2) + r;
      const float sc = routed ? rowscale[row] : scales[row * 4 + 2];
#pragma unroll
      for (int cf = 0; cf < 2; ++cf) {
        const int col = col0 + wc + cf * 16 + (lane & 15);
        float g = accG[fr][cf][r];
        float u = accU[fr][cf][r];
        float a = 0.5f * g * (1.0f + erff(g * 0.70710678118654752f));
        Out[(size_t)row * outLd + col] = f2b(a * u * sc);
      }
    }
}

// ---------------- GEMM2: down-projection, 128x128 m97 shape (r7) -------------
// ROUTED: out_r[row][h] = Bg[row] @ down_e  (bf16), K=512.  grid (8, 72)
// SHARED: out[t][h] = Bs[t] @ down_s + out_r[r0][h] + out_r[r1][h] (f32). (8,32)
template<int ROUTED>
__global__ __launch_bounds__(256) void gemm2_k(
    const ushort* __restrict__ A, const ushort* __restrict__ DT,
    const int* __restrict__ meta, const int* __restrict__ tokrows,
    const ushort* __restrict__ Rrows, ushort* __restrict__ OutB,
    float* __restrict__ OutF)
{
  __shared__ __align__(16) ushort lA[128 * 64];
  __shared__ __align__(16) ushort lB[128 * 64];
  int e = 0;
  if (ROUTED) {
    if ((int)blockIdx.y >= meta[511]) return;
    e = meta[320 + blockIdx.y];
  }
  const int K = ROUTED ? 512 : 1024;
  const int bBase = ROUTED ? e * 512 : 4096;
  const int tid = threadIdx.x, wid = tid >> 6, lane = tid & 63;
  const int col0 = blockIdx.x * 128, row0 = blockIdx.y * 128;
  const int wr = (wid >> 1) * 64, wc = (wid & 1) * 64;

  int aOff[4], bOff[4], lds[4];
#pragma unroll
  for (int i = 0; i < 4; ++i) {
    int q = i * 256 + tid;
    int r = q >> 3, c = q & 7, lc = c ^ (r & 7);
    aOff[i] = (row0 + r) * K + lc * 8;
    bOff[i] = (col0 + r) * 5120 + bBase + lc * 8;
    lds[i]  = (i * 256 + (tid & ~63)) * 8;
  }
  f32x4 acc[4][4] = {};
  for (int k0 = 0; k0 < K; k0 += 64) {
    if (k0) __syncthreads();
#pragma unroll
    for (int i = 0; i < 4; ++i) gll16(A + aOff[i] + k0, lA + lds[i]);
#pragma unroll
    for (int i = 0; i < 4; ++i) gll16(DT + bOff[i] + k0, lB + lds[i]);
    __syncthreads();
#pragma unroll
    for (int kc = 0; kc < 2; ++kc) {
      const int clog = kc * 4 + (lane >> 4);
      s16x8 af[4], bf[4];
#pragma unroll
      for (int fr = 0; fr < 4; ++fr) {
        int rl = wr + fr * 16 + (lane & 15);
        af[fr] = *(const s16x8*)&lA[rl * 64 + ((clog ^ (rl & 7)) << 3)];
      }
#pragma unroll
      for (int cf = 0; cf < 4; ++cf) {
        int cl = wc + cf * 16 + (lane & 15);
        bf[cf] = *(const s16x8*)&lB[cl * 64 + ((clog ^ (cl & 7)) << 3)];
      }
#pragma unroll
      for (int fr = 0; fr < 4; ++fr)
#pragma unroll
        for (int cf = 0; cf < 4; ++cf)
          acc[fr][cf] = mfma_bf16(af[fr], bf[cf], acc[fr][cf]);
    }
  }
#pragma unroll
  for (int fr = 0; fr < 4; ++fr)
#pragma unroll
    for (int r = 0; r < 4; ++r) {
      const int row = row0 + wr + fr * 16 + ((lane >> 4) << 2) + r;
      if (ROUTED) {
#pragma unroll
        for (int cf = 0; cf < 4; ++cf) {
          const int col = col0 + wc + cf * 16 + (lane & 15);
          OutB[row * 1024 + col] = f2b(acc[fr][cf][r]);
        }
      } else {
        const int r0 = tokrows[row * 2], r1 = tokrows[row * 2 + 1];
#pragma unroll
        for (int cf = 0; cf < 4; ++cf) {
          const int col = col0 + wc + cf * 16 + (lane & 15);
          float v = acc[fr][cf][r]
                  + b2f(Rrows[r0 * 1024 + col]) + b2f(Rrows[r1 * 1024 + col]);
          OutF[row * 1024 + col] = v;
        }
      }
    }
}

extern "C" void kernel_launch(void* const* d_in, const int* in_sizes, int n_in,
                              void* d_out, int out_size, void* d_ws, size_t ws_size,
                              hipStream_t stream) {
  const float* X    = (const float*)d_in[0];   // [4096,1024]
  const int*   task = (const int*)  d_in[1];
  const float* Gw   = (const float*)d_in[2];   // [8,1024]
  const float* Temb = (const float*)d_in[3];   // [3,1024]
  const float* Weg  = (const float*)d_in[4];   // [8,1024,512]
  const float* Weu  = (const float*)d_in[5];   // [8,1024,512]
  const float* Wed  = (const float*)d_in[6];   // [8,512,1024]
  const float* Wsg  = (const float*)d_in[7];   // [1024,1024]
  const float* Wsu  = (const float*)d_in[8];   // [1024,1024]
  const float* Wsd  = (const float*)d_in[9];   // [1024,1024]
  const float* Wc   = (const float*)d_in[10];  // [1024,2]

  char* ws = (char*)d_ws;
  float*  scales   = (float*)(ws + 0x00000);        // 4096*4 f32
  int*    topk     = (int*)  (ws + 0x10000);        // 4096*2
  int*    tokmap   = (int*)  (ws + 0x18000);        // <=9216
  int*    tokrows  = (int*)  (ws + 0x22000);        // 4096*2
  float*  rowscale = (float*)(ws + 0x2A000);        // <=9216
  int*    meta     = (int*)  (ws + 0x34000);        // 512
  ushort* Xb       = (ushort*)(ws + 0x40000);       // 4096*1024
  ushort* GT       = Xb + 4096 * 1024;              // 5120*1024
  ushort* UT       = GT + 5120 * 1024;
  ushort* DT       = UT + 5120 * 1024;              // 1024*5120
  ushort* Bg       = DT + 1024 * 5120;              // 9216*512
  ushort* Bs       = Bg + 9216 * 512;               // 4096*1024
  ushort* out_r    = Bs + 4096 * 1024;              // 9216*1024

  prep_k<<<16384, 256, 0, stream>>>(X, Gw, Temb, task, Wc,
                                    Weg, Weu, Wed, Wsg, Wsu, Wsd,
                                    GT, UT, DT, scales, topk, Xb);
  indexbuild_k<<<1, 256, 0, stream>>>(topk, scales, tokmap, tokrows, rowscale, meta);

  gemm1_k<<<dim3(16, 208), 256, 0, stream>>>(Xb, GT, UT, scales, tokmap, rowscale, meta, Bg, Bs);

  gemm2_k<1><<<dim3(8, 72), 256, 0, stream>>>(Bg, DT, meta, tokrows, (const ushort*)nullptr, out_r, (float*)nullptr);
  gemm2_k<0><<<dim3(8, 32), 256, 0, stream>>>(Bs, DT, meta, tokrows, out_r, (ushort*)nullptr, (float*)d_out);
}